// Round 7
// baseline (206.787 us; speedup 1.0000x reference)
//
#include <hip/hip_runtime.h>
#include <stdint.h>

namespace {

constexpr int IN_F = 1024;
constexpr int OUT_F = 1024;
constexpr int GSZ = 8;
constexpr int KTOT = IN_F + IN_F * GSZ;   // 9216
constexpr int BK = 64;
constexpr int NT = KTOT / BK;             // 144 (even)
constexpr int NBASE = IN_F / BK;          // 16 base-path steps

// fast-path geometry: 64x256 tile, 8 waves (wave tile 32x64), 2 blocks/CU
constexpr int BM = 64, BN = 256;
constexpr int NBLK = OUT_F / BN;          // 4
constexpr size_t IMG_BYTES = (size_t)BN * BK * 2;              // 32 KB per (nb,step)
constexpr size_t WS_NEEDED = (size_t)NBLK * NT * IMG_BYTES;    // 18.87 MB

constexpr double H_D     = 4.0 / 7.0;
constexpr double INVD_D  = 1.0 / (H_D + 1e-6);
constexpr double L2E_D   = 1.4426950408889634;
constexpr double SQL2E_D = 1.2011224087864498;       // sqrt(log2 e)
constexpr double CS_D    = INVD_D * SQL2E_D;         // exp(-(d*invd)^2)=exp2(-((d*CS)^2))
constexpr double DLT_D   = H_D * CS_D;               // grid spacing, scaled

using short8 = __attribute__((ext_vector_type(8))) short;
using f32x4  = __attribute__((ext_vector_type(4))) float;

__device__ __forceinline__ unsigned cvt_pk(float lo, float hi) {
  unsigned r;
  asm("v_cvt_pk_bf16_f32 %0, %1, %2" : "=v"(r) : "v"(lo), "v"(hi));
  return r;
}
__device__ __forceinline__ float silu_f(float v) {
  float e = __builtin_amdgcn_exp2f(-v * (float)L2E_D);
  return v * __builtin_amdgcn_rcpf(1.0f + e);
}
// XOR-swizzled byte offset in a [rows][64 bf16] tile, row stride 128B.
__device__ __forceinline__ int swz(int row, int kk) {
  return (row * 128 + kk * 2) ^ ((row & 7) << 4);
}

// ---------------- weight prep: f32 -> bf16, swizzled LDS images ----------------
__global__ void wprep(const float* __restrict__ bw, const float* __restrict__ sw,
                      char* __restrict__ wimg)
{
  const int total = NBLK * NT * BN * 8;   // 16B chunks (8 bf16 each)
  for (int idx = blockIdx.x * blockDim.x + threadIdx.x; idx < total;
       idx += gridDim.x * blockDim.x) {
    const int kk8  = idx & 7;
    const int row  = (idx >> 3) & (BN - 1);
    const int rest = idx >> 11;           // nb*NT + step
    const int step = rest % NT;
    const int nb   = rest / NT;
    const int o    = nb * BN + row;
    const int k    = step * BK + kk8 * 8;
    const float* src = (k < IN_F)
      ? (bw + (size_t)o * IN_F + k)
      : (sw + (size_t)o * (size_t)(IN_F * GSZ) + (k - IN_F));
    const float4 a = ((const float4*)src)[0];
    const float4 b = ((const float4*)src)[1];
    int4 v;
    v.x = (int)cvt_pk(a.x, a.y);
    v.y = (int)cvt_pk(a.z, a.w);
    v.z = (int)cvt_pk(b.x, b.y);
    v.w = (int)cvt_pk(b.z, b.w);
    *(int4*)(wimg + (size_t)rest * IMG_BYTES + swz(row, kk8 * 8)) = v;
  }
}

// ------------- fast main kernel: 64x256 tile, 8 waves, 4 waves/SIMD -------------
__global__ __launch_bounds__(512, 4)
void kan_fast(const float* __restrict__ x, const float* __restrict__ bb,
              const char* __restrict__ wimg, float* __restrict__ out)
{
  __shared__ char tA[2][BM * BK * 2];     // 2 x 8 KB, swizzled
  __shared__ char tB[2][BN * BK * 2];     // 2 x 32 KB, swizzled (baked in image)

  const int t    = threadIdx.x;
  const int lane = t & 63;
  const int wid  = t >> 6;                // 0..7
  const int wr   = (wid >> 2) * 32;       // wave row offset (wave tile 32x64)
  const int wc   = (wid & 3) * 64;        // wave col offset
  const int bm0  = blockIdx.y * BM;
  const char* img = wimg + (size_t)blockIdx.x * NT * IMG_BYTES;
  const int bn0  = blockIdx.x * BN;

  const float CSf  = (float)CS_D;
  const float C0f  = (float)(-2.0 * CS_D);
  const float TDLT = (float)(2.0 * DLT_D);
  float Kc[7];
#pragma unroll
  for (int g = 0; g < 7; ++g) {
    const double cg  = (-2.0 + g * H_D) * CS_D;
    const double cg1 = (-2.0 + (g + 1) * H_D) * CS_D;
    Kc[g] = __builtin_amdgcn_exp2f((float)(-DLT_D * (cg + cg1)));
  }

  f32x4 acc[2][4];
#pragma unroll
  for (int m = 0; m < 2; ++m)
#pragma unroll
    for (int n = 0; n < 4; ++n) acc[m][n] = (f32x4)0.0f;

  float4 xE[2], xO[2];                    // ping-pong x prefetch (static indexing only)

  // per-wave glds source base: identity image->LDS mapping, wave-contiguous 4KB
  const char* gB = img + wid * 4096 + lane * 16;

  // issue full B(step) image into dstB: 4 x global_load_lds(16B), imm offsets
  auto issue_B = [&](int step, char* dstB) {
    const char* g = gB + (size_t)step * IMG_BYTES;
    char* l = dstB + wid * 4096;          // wave-uniform LDS base
#pragma unroll
    for (int j = 0; j < 4; ++j)
      __builtin_amdgcn_global_load_lds(
        (const __attribute__((address_space(1))) void*)(g + j * 1024),
        (__attribute__((address_space(3))) void*)(l + j * 1024), 16, 0, 0);
  };

  auto load_x = [&](int step, float4 (&xr)[2]) {
    const int k0  = step * BK;
    const int row = t >> 3;               // 0..63
    if (k0 < IN_F) {
      const float* p = x + (size_t)(bm0 + row) * IN_F + k0 + (t & 7) * 8;
      xr[0] = ((const float4*)p)[0];
      xr[1] = ((const float4*)p)[1];
    } else {
      const int i0 = (k0 - IN_F) >> 3;
      xr[0].x = x[(size_t)(bm0 + row) * IN_F + i0 + (t & 7)];
    }
  };

  auto conv_A = [&](int step, const float4 (&xr)[2], char* dstA) {
    const int row = t >> 3;
    char* dst = dstA + swz(row, (t & 7) * 8);   // one 16B slot per thread
    if (step < NBASE) {
      unsigned q0 = cvt_pk(silu_f(xr[0].x), silu_f(xr[0].y));
      unsigned q1 = cvt_pk(silu_f(xr[0].z), silu_f(xr[0].w));
      unsigned q2 = cvt_pk(silu_f(xr[1].x), silu_f(xr[1].y));
      unsigned q3 = cvt_pk(silu_f(xr[1].z), silu_f(xr[1].w));
      *(int4*)dst = make_int4(q0, q1, q2, q3);
    } else {
      const float tb = xr[0].x * CSf;
      const float d0 = tb - C0f;
      float e = __builtin_amdgcn_exp2f(-(d0 * d0));   // e_0
      const float r = __builtin_amdgcn_exp2f(tb * TDLT);
      unsigned q[4];
#pragma unroll
      for (int g = 0; g < 4; ++g) {
        const float a = e;                  // e_{2g}
        const float b = a * r * Kc[2 * g];  // e_{2g+1}
        q[g] = cvt_pk(a, b);
        if (g < 3) e = b * r * Kc[2 * g + 1];
      }
      *(int4*)dst = make_int4(q[0], q[1], q[2], q[3]);
    }
  };

  auto read_frags = [&](const char* A, const char* B, int kh,
                        short8 (&af)[2], short8 (&bf)[4]) {
    const int r  = lane & 15;
    const int kq = (lane >> 4) * 8;
#pragma unroll
    for (int m = 0; m < 2; ++m)
      af[m] = *(const short8*)(A + swz(wr + m * 16 + r, kh * 32 + kq));
#pragma unroll
    for (int n = 0; n < 4; ++n)
      bf[n] = *(const short8*)(B + swz(wc + n * 16 + r, kh * 32 + kq));
  };

  auto mfma8 = [&](short8 (&af)[2], short8 (&bf)[4]) {
#pragma unroll
    for (int m = 0; m < 2; ++m)
#pragma unroll
      for (int n = 0; n < 4; ++n)
        acc[m][n] = __builtin_amdgcn_mfma_f32_16x16x32_bf16(af[m], bf[n], acc[m][n], 0, 0, 0);
  };

  // one K-step: single MFMA phase, 2 barriers, counted vmcnt (never 0 mid-loop)
  auto step_body = [&](int s, char* curA, char* curB, char* nxtA, char* nxtB,
                       const float4 (&xconv)[2], float4 (&xload)[2]) {
    short8 a0[2], b0[4], a1[2], b1[4];
    read_frags(curA, curB, 0, a0, b0);     // kh=0 frags (fly under stage work)
    if (s + 1 < NT) issue_B(s + 1, nxtB);  // 4 glds -> nxtB
    __builtin_amdgcn_sched_barrier(0);     // pin glds before x-loads (vmcnt counting)
    if (s + 2 < NT) load_x(s + 2, xload);
    if (s + 1 < NT) conv_A(s + 1, xconv, nxtA);   // VALU + ds_write -> nxtA
    __builtin_amdgcn_s_barrier();
    asm volatile("s_waitcnt lgkmcnt(0)" ::: "memory");   // kh0 frags + my A-write done
    __builtin_amdgcn_sched_barrier(0);
    __builtin_amdgcn_s_setprio(1);
    read_frags(curA, curB, 1, a1, b1);     // kh=1 frags hide under kh0 MFMAs
    mfma8(a0, b0);
    asm volatile("s_waitcnt lgkmcnt(0)" ::: "memory");
    __builtin_amdgcn_sched_barrier(0);
    mfma8(a1, b1);
    __builtin_amdgcn_s_setprio(0);
    if (s + 2 < NT) {
      asm volatile("s_waitcnt vmcnt(1)" ::: "memory");   // glds done (>=4+nx-1 retired)
    } else {
      asm volatile("s_waitcnt vmcnt(0)" ::: "memory");   // tail: full drain
    }
    __builtin_amdgcn_s_barrier();          // publish nxtA/nxtB
  };

  // prologue
  load_x(0, xE);
  load_x(1, xO);
  issue_B(0, tB[0]);
  conv_A(0, xE, tA[0]);
  __syncthreads();                   // full drain once: B(0)+A(0) visible

  for (int s = 0; s < NT; s += 2) {
    step_body(s,     tA[0], tB[0], tA[1], tB[1], xO, xE);
    step_body(s + 1, tA[1], tB[1], tA[0], tB[0], xE, xO);
  }

  // epilogue: C/D mapping col=lane&15, row=(lane>>4)*4+reg (verified r2-r6)
  const int col = lane & 15;
  const int rr  = (lane >> 4) * 4;
#pragma unroll
  for (int m = 0; m < 2; ++m) {
    const int gr = bm0 + wr + m * 16 + rr;
#pragma unroll
    for (int n = 0; n < 4; ++n) {
      const int gc = bn0 + wc + n * 16 + col;
      const float bias = bb[gc];
#pragma unroll
      for (int j = 0; j < 4; ++j)
        out[(size_t)(gr + j) * OUT_F + gc] = acc[m][n][j] + bias;
    }
  }
}

// ---------------- fallback: round-2 verified kernel (unchanged) ----------------
constexpr int SLDK = 64 + 8;

__device__ __forceinline__ unsigned f2bf(float f) {
  unsigned u = __float_as_uint(f);
  return (u + 0x7fffu + ((u >> 16) & 1u)) >> 16;
}
__device__ __forceinline__ unsigned pk2(float lo, float hi) {
  return f2bf(lo) | (f2bf(hi) << 16);
}

__global__ __launch_bounds__(256)
void kan_slow(const float* __restrict__ x, const float* __restrict__ bw,
              const float* __restrict__ bb, const float* __restrict__ sw,
              float* __restrict__ out)
{
  __shared__ unsigned short tA[128][SLDK];
  __shared__ unsigned short tB[128][SLDK];

  const int t    = threadIdx.x;
  const int lane = t & 63;
  const int wid  = t >> 6;
  const int wr   = (wid >> 1) * 64;
  const int wc   = (wid & 1) * 64;
  const int bm0  = blockIdx.x * 128;
  const int bn0  = blockIdx.y * 128;

  const float CS = (float)CS_D;
  float gsc[GSZ];
#pragma unroll
  for (int g = 0; g < GSZ; ++g)
    gsc[g] = (float)((-2.0 + g * H_D) * CS_D);

  f32x4 acc[4][4];
#pragma unroll
  for (int m = 0; m < 4; ++m)
#pragma unroll
    for (int n = 0; n < 4; ++n) acc[m][n] = (f32x4)0.0f;

  float4 rA[8], rB[8];
  const int rw = t >> 4;
  const int cw = (t & 15) * 4;

  auto load_tile = [&](int step) {
    const int k0 = step * BK;
    const bool base = (k0 < IN_F);
#pragma unroll
    for (int j = 0; j < 8; ++j) {
      const int row = j * 16 + rw;
      const float* p = base
        ? (bw + (size_t)(bn0 + row) * IN_F + k0 + cw)
        : (sw + (size_t)(bn0 + row) * (size_t)(IN_F * GSZ) + (k0 - IN_F) + cw);
      rB[j] = *(const float4*)p;
    }
    if (base) {
#pragma unroll
      for (int j = 0; j < 8; ++j) {
        const int row = j * 16 + rw;
        rA[j] = *(const float4*)(x + (size_t)(bm0 + row) * IN_F + k0 + cw);
      }
    } else {
      const int i0  = (k0 - IN_F) >> 3;
      const int row = t >> 1;
      rA[0] = *(const float4*)(x + (size_t)(bm0 + row) * IN_F + i0 + (t & 1) * 4);
    }
  };

  auto store_tile = [&](int step) {
    const int k0 = step * BK;
    const bool base = (k0 < IN_F);
#pragma unroll
    for (int j = 0; j < 8; ++j) {
      const int row = j * 16 + rw;
      uint2 v;
      v.x = pk2(rB[j].x, rB[j].y);
      v.y = pk2(rB[j].z, rB[j].w);
      *(uint2*)&tB[row][cw] = v;
    }
    if (base) {
#pragma unroll
      for (int j = 0; j < 8; ++j) {
        const int row = j * 16 + rw;
        uint2 v;
        v.x = pk2(silu_f(rA[j].x), silu_f(rA[j].y));
        v.y = pk2(silu_f(rA[j].z), silu_f(rA[j].w));
        *(uint2*)&tA[row][cw] = v;
      }
    } else {
      const int row  = t >> 1;
      const int half = t & 1;
      const float* xv = (const float*)&rA[0];
#pragma unroll
      for (int c = 0; c < 4; ++c) {
        const float tb = xv[c] * CS;
        union { unsigned u[4]; int4 v4; } pkv;
#pragma unroll
        for (int g = 0; g < 8; g += 2) {
          const float t0 = tb - gsc[g];
          const float t1 = tb - gsc[g + 1];
          const float e0 = __builtin_amdgcn_exp2f(-(t0 * t0));
          const float e1 = __builtin_amdgcn_exp2f(-(t1 * t1));
          pkv.u[g >> 1] = pk2(e0, e1);
        }
        const int kc = (half * 4 + c) * 8;
        *(int4*)&tA[row][kc] = pkv.v4;
      }
    }
  };

  auto compute_tile = [&]() {
    const int r  = lane & 15;
    const int kq = (lane >> 4) * 8;
#pragma unroll
    for (int kh = 0; kh < 2; ++kh) {
      short8 af[4], bf[4];
#pragma unroll
      for (int m = 0; m < 4; ++m)
        af[m] = *(const short8*)&tA[wr + m * 16 + r][kh * 32 + kq];
#pragma unroll
      for (int n = 0; n < 4; ++n)
        bf[n] = *(const short8*)&tB[wc + n * 16 + r][kh * 32 + kq];
#pragma unroll
      for (int m = 0; m < 4; ++m)
#pragma unroll
        for (int n = 0; n < 4; ++n)
          acc[m][n] = __builtin_amdgcn_mfma_f32_16x16x32_bf16(af[m], bf[n], acc[m][n], 0, 0, 0);
    }
  };

  load_tile(0);
  for (int step = 0; step < NT; ++step) {
    store_tile(step);
    __syncthreads();
    if (step + 1 < NT) load_tile(step + 1);
    compute_tile();
    __syncthreads();
  }

  const int col = lane & 15;
  const int rr  = (lane >> 4) * 4;
#pragma unroll
  for (int m = 0; m < 4; ++m) {
    const int gr = bm0 + wr + m * 16 + rr;
#pragma unroll
    for (int n = 0; n < 4; ++n) {
      const int gc = bn0 + wc + n * 16 + col;
      const float bias = bb[gc];
#pragma unroll
      for (int j = 0; j < 4; ++j)
        out[(size_t)(gr + j) * OUT_F + gc] = acc[m][n][j] + bias;
    }
  }
}

} // namespace

extern "C" void kernel_launch(void* const* d_in, const int* in_sizes, int n_in,
                              void* d_out, int out_size, void* d_ws, size_t ws_size,
                              hipStream_t stream) {
  const float *x, *bw, *bb, *sw;
  if (in_sizes[0] == OUT_F) {            // alphabetical order guard
    bb = (const float*)d_in[0];
    bw = (const float*)d_in[1];
    sw = (const float*)d_in[2];
    x  = (const float*)d_in[3];
  } else {
    x  = (const float*)d_in[0];
    bw = (const float*)d_in[1];
    bb = (const float*)d_in[2];
    sw = (const float*)d_in[3];
  }
  float* out = (float*)d_out;
  const int rows = (in_sizes[0] == OUT_F) ? in_sizes[3] / IN_F : in_sizes[0] / IN_F;

  if (ws_size >= WS_NEEDED && d_ws != nullptr && (rows % BM) == 0) {
    hipLaunchKernelGGL(wprep, dim3(2048), dim3(256), 0, stream, bw, sw, (char*)d_ws);
    dim3 grid(NBLK, rows / BM);          // 4 x 128 = 512 blocks -> 2 blocks/CU
    hipLaunchKernelGGL(kan_fast, grid, dim3(512), 0, stream,
                       x, bb, (const char*)d_ws, out);
  } else {
    dim3 grid(rows / 128, OUT_F / 128);
    hipLaunchKernelGGL(kan_slow, grid, dim3(256), 0, stream, x, bw, bb, sw, out);
  }
}

// Round 8
// 198.506 us; speedup vs baseline: 1.0417x; 1.0417x over previous
//
#include <hip/hip_runtime.h>
#include <stdint.h>

namespace {

constexpr int IN_F = 1024;
constexpr int OUT_F = 1024;
constexpr int GSZ = 8;
constexpr int KTOT = IN_F + IN_F * GSZ;   // 9216
constexpr int BK = 64;
constexpr int NT = KTOT / BK;             // 144
constexpr int NBASE = IN_F / BK;          // 16 base-path steps

// fast-path geometry: 64x256 tile, 8 waves (4 consumer + 4 producer), 2 blocks/CU
constexpr int BM = 64, BN = 256;
constexpr int NBLK = OUT_F / BN;          // 4
constexpr size_t IMG_BYTES = (size_t)BN * BK * 2;              // 32 KB per (nb,step)
constexpr size_t WS_NEEDED = (size_t)NBLK * NT * IMG_BYTES;    // 18.87 MB

constexpr double H_D     = 4.0 / 7.0;
constexpr double INVD_D  = 1.0 / (H_D + 1e-6);
constexpr double L2E_D   = 1.4426950408889634;
constexpr double SQL2E_D = 1.2011224087864498;       // sqrt(log2 e)
constexpr double CS_D    = INVD_D * SQL2E_D;         // exp(-(d*invd)^2)=exp2(-((d*CS)^2))
constexpr double DLT_D   = H_D * CS_D;               // grid spacing, scaled

using short8 = __attribute__((ext_vector_type(8))) short;
using f32x4  = __attribute__((ext_vector_type(4))) float;

__device__ __forceinline__ unsigned cvt_pk(float lo, float hi) {
  unsigned r;
  asm("v_cvt_pk_bf16_f32 %0, %1, %2" : "=v"(r) : "v"(lo), "v"(hi));
  return r;
}
__device__ __forceinline__ float silu_f(float v) {
  float e = __builtin_amdgcn_exp2f(-v * (float)L2E_D);
  return v * __builtin_amdgcn_rcpf(1.0f + e);
}
// XOR-swizzled byte offset in a [rows][64 bf16] tile, row stride 128B.
__device__ __forceinline__ int swz(int row, int kk) {
  return (row * 128 + kk * 2) ^ ((row & 7) << 4);
}

// ---------------- weight prep: f32 -> bf16, swizzled LDS images ----------------
__global__ void wprep(const float* __restrict__ bw, const float* __restrict__ sw,
                      char* __restrict__ wimg)
{
  const int total = NBLK * NT * BN * 8;   // 16B chunks (8 bf16 each)
  for (int idx = blockIdx.x * blockDim.x + threadIdx.x; idx < total;
       idx += gridDim.x * blockDim.x) {
    const int kk8  = idx & 7;
    const int row  = (idx >> 3) & (BN - 1);
    const int rest = idx >> 11;           // nb*NT + step
    const int step = rest % NT;
    const int nb   = rest / NT;
    const int o    = nb * BN + row;
    const int k    = step * BK + kk8 * 8;
    const float* src = (k < IN_F)
      ? (bw + (size_t)o * IN_F + k)
      : (sw + (size_t)o * (size_t)(IN_F * GSZ) + (k - IN_F));
    const float4 a = ((const float4*)src)[0];
    const float4 b = ((const float4*)src)[1];
    int4 v;
    v.x = (int)cvt_pk(a.x, a.y);
    v.y = (int)cvt_pk(a.z, a.w);
    v.z = (int)cvt_pk(b.x, b.y);
    v.w = (int)cvt_pk(b.z, b.w);
    *(int4*)(wimg + (size_t)rest * IMG_BYTES + swz(row, kk8 * 8)) = v;
  }
}

// -------- fast main kernel: producer/consumer wave split, 1 barrier/step --------
__global__ __launch_bounds__(512, 4)
void kan_fast(const float* __restrict__ x, const float* __restrict__ bb,
              const char* __restrict__ wimg, float* __restrict__ out)
{
  __shared__ char tA[2][BM * BK * 2];     // 2 x 8 KB, swizzled
  __shared__ char tB[2][BN * BK * 2];     // 2 x 32 KB, swizzled (baked in image)

  const int t    = threadIdx.x;
  const int lane = t & 63;
  const int wid  = t >> 6;                // 0..7
  const bool cons = (wid < 4);            // waves 0-3 = MFMA consumers
  const int wc   = (wid & 3) * 64;        // consumer col offset (wave tile 64x64)
  const int bm0  = blockIdx.y * BM;
  const char* img = wimg + (size_t)blockIdx.x * NT * IMG_BYTES;
  const int bn0  = blockIdx.x * BN;

  const float CSf  = (float)CS_D;
  const float C0f  = (float)(-2.0 * CS_D);
  const float TDLT = (float)(2.0 * DLT_D);
  float Kc[7];
#pragma unroll
  for (int g = 0; g < 7; ++g) {
    const double cg  = (-2.0 + g * H_D) * CS_D;
    const double cg1 = (-2.0 + (g + 1) * H_D) * CS_D;
    Kc[g] = __builtin_amdgcn_exp2f((float)(-DLT_D * (cg + cg1)));
  }

  f32x4 acc[4][4];                        // consumers only (touched in cons path)
#pragma unroll
  for (int m = 0; m < 4; ++m)
#pragma unroll
    for (int n = 0; n < 4; ++n) acc[m][n] = (f32x4)0.0f;

  // ---------------- producer helpers (lanes 256..511, t2 = 0..255) ----------------
  const int t2   = t & 255;               // producer-local index
  const int prow = t2 >> 2;               // 0..63 (A-tile row)
  const int pcol = t2 & 3;
  const int pw   = wid & 3;               // producer wave 0..3

  float4 xr[4];                           // x prefetch (single buffer, WAR-ordered)

  auto issue_B = [&](int step, char* dstB) {
    // 8 chunks of 1KB per producer wave; identity image->LDS mapping
    const char* g = img + (size_t)step * IMG_BYTES + pw * 8192 + lane * 16;
    char* l = dstB + pw * 8192 + lane * 16;
#pragma unroll
    for (int j = 0; j < 8; ++j)
      __builtin_amdgcn_global_load_lds(
        (const __attribute__((address_space(1))) void*)(g + j * 1024),
        (__attribute__((address_space(3))) void*)(l + j * 1024), 16, 0, 0);
  };

  auto load_x = [&](int step) {
    const int k0 = step * BK;
    if (k0 < IN_F) {                      // base: 16 f32/lane
      const float* p = x + (size_t)(bm0 + prow) * IN_F + k0 + pcol * 16;
#pragma unroll
      for (int j = 0; j < 4; ++j) xr[j] = ((const float4*)p)[j];
    } else {                              // spline: 2 f32/lane
      const int i0 = (k0 - IN_F) >> 3;
      const float2 v = *(const float2*)(x + (size_t)(bm0 + prow) * IN_F + i0 + pcol * 2);
      xr[0].x = v.x; xr[0].y = v.y;
    }
  };

  auto conv_A = [&](int step, char* dstA) {
    if (step < NBASE) {
      unsigned q[8];
#pragma unroll
      for (int j = 0; j < 4; ++j) {
        q[2 * j]     = cvt_pk(silu_f(xr[j].x), silu_f(xr[j].y));
        q[2 * j + 1] = cvt_pk(silu_f(xr[j].z), silu_f(xr[j].w));
      }
      const int kc0 = pcol * 16;
      *(int4*)(dstA + swz(prow, kc0))     = make_int4(q[0], q[1], q[2], q[3]);
      *(int4*)(dstA + swz(prow, kc0 + 8)) = make_int4(q[4], q[5], q[6], q[7]);
    } else {
#pragma unroll
      for (int c = 0; c < 2; ++c) {
        const float xv = c ? xr[0].y : xr[0].x;
        const float tb = xv * CSf;
        const float d0 = tb - C0f;
        float e = __builtin_amdgcn_exp2f(-(d0 * d0));   // e_0
        const float r = __builtin_amdgcn_exp2f(tb * TDLT);
        unsigned q[4];
#pragma unroll
        for (int g = 0; g < 4; ++g) {
          const float a = e;                  // e_{2g}
          const float b = a * r * Kc[2 * g];  // e_{2g+1}
          q[g] = cvt_pk(a, b);
          if (g < 3) e = b * r * Kc[2 * g + 1];
        }
        *(int4*)(dstA + swz(prow, (pcol * 2 + c) * 8)) = make_int4(q[0], q[1], q[2], q[3]);
      }
    }
  };

  // producer end-of-step drain: glds retired, x-prefetch may stay in flight
  auto prod_drain = [&](int s) {
    if (s + 2 < NBASE) {
      asm volatile("s_waitcnt vmcnt(4) lgkmcnt(0)" ::: "memory");
    } else if (s + 2 < NT) {
      asm volatile("s_waitcnt vmcnt(1) lgkmcnt(0)" ::: "memory");
    } else {
      asm volatile("s_waitcnt vmcnt(0) lgkmcnt(0)" ::: "memory");
    }
    __builtin_amdgcn_sched_barrier(0);
  };

  // ---------------- consumer helper ----------------
  const int fr = lane & 15;
  const int kq = (lane >> 4) * 8;

  auto consume = [&](const char* curA, const char* curB) {
    short8 af[4], bf[4];
    __builtin_amdgcn_s_setprio(1);
#pragma unroll
    for (int kh = 0; kh < 2; ++kh) {
#pragma unroll
      for (int m = 0; m < 4; ++m)
        af[m] = *(const short8*)(curA + swz(m * 16 + fr, kh * 32 + kq));
#pragma unroll
      for (int n = 0; n < 4; ++n)
        bf[n] = *(const short8*)(curB + swz(wc + n * 16 + fr, kh * 32 + kq));
#pragma unroll
      for (int m = 0; m < 4; ++m)
#pragma unroll
        for (int n = 0; n < 4; ++n)
          acc[m][n] = __builtin_amdgcn_mfma_f32_16x16x32_bf16(af[m], bf[n], acc[m][n], 0, 0, 0);
    }
    __builtin_amdgcn_s_setprio(0);
  };

  // ---------------- prologue ----------------
  if (!cons) {
    load_x(0);
    conv_A(0, tA[0]);
    issue_B(0, tB[0]);
    load_x(1);                            // WAR: issued after conv_A(0) reads
    asm volatile("s_waitcnt vmcnt(0) lgkmcnt(0)" ::: "memory");
    __builtin_amdgcn_sched_barrier(0);
  }
  __builtin_amdgcn_s_barrier();           // A(0)/B(0) published

  // ---------------- main loop: 1 barrier per step ----------------
  int cur = 0;
  for (int s = 0; s < NT; ++s) {
    char* curA = tA[cur];
    char* curB = tB[cur];
    char* nxtA = tA[cur ^ 1];
    char* nxtB = tB[cur ^ 1];
    if (cons) {
      consume(curA, curB);                // 32 MFMA + 16 ds_read_b128, no VMEM
    } else {
      if (s + 1 < NT) {
        issue_B(s + 1, nxtB);             // async DMA -> nxtB
        conv_A(s + 1, nxtA);              // VALU + ds_write -> nxtA (uses x(s+1))
        if (s + 2 < NT) load_x(s + 2);    // prefetch next x (WAR after conv)
        prod_drain(s);
      }
    }
    __builtin_amdgcn_s_barrier();         // publish nxtA/nxtB; curA/curB reads done
    cur ^= 1;
  }

  // ---------------- epilogue (consumers only) ----------------
  if (cons) {
    const int col = lane & 15;
    const int rr  = (lane >> 4) * 4;
#pragma unroll
    for (int m = 0; m < 4; ++m) {
      const int gr = bm0 + m * 16 + rr;
#pragma unroll
      for (int n = 0; n < 4; ++n) {
        const int gc = bn0 + wc + n * 16 + col;
        const float bias = bb[gc];
#pragma unroll
        for (int j = 0; j < 4; ++j)
          out[(size_t)(gr + j) * OUT_F + gc] = acc[m][n][j] + bias;
      }
    }
  }
}

// ---------------- fallback: round-2 verified kernel (unchanged) ----------------
constexpr int SLDK = 64 + 8;

__device__ __forceinline__ unsigned f2bf(float f) {
  unsigned u = __float_as_uint(f);
  return (u + 0x7fffu + ((u >> 16) & 1u)) >> 16;
}
__device__ __forceinline__ unsigned pk2(float lo, float hi) {
  return f2bf(lo) | (f2bf(hi) << 16);
}

__global__ __launch_bounds__(256)
void kan_slow(const float* __restrict__ x, const float* __restrict__ bw,
              const float* __restrict__ bb, const float* __restrict__ sw,
              float* __restrict__ out)
{
  __shared__ unsigned short tA[128][SLDK];
  __shared__ unsigned short tB[128][SLDK];

  const int t    = threadIdx.x;
  const int lane = t & 63;
  const int wid  = t >> 6;
  const int wr   = (wid >> 1) * 64;
  const int wc   = (wid & 1) * 64;
  const int bm0  = blockIdx.x * 128;
  const int bn0  = blockIdx.y * 128;

  const float CS = (float)CS_D;
  float gsc[GSZ];
#pragma unroll
  for (int g = 0; g < GSZ; ++g)
    gsc[g] = (float)((-2.0 + g * H_D) * CS_D);

  f32x4 acc[4][4];
#pragma unroll
  for (int m = 0; m < 4; ++m)
#pragma unroll
    for (int n = 0; n < 4; ++n) acc[m][n] = (f32x4)0.0f;

  float4 rA[8], rB[8];
  const int rw = t >> 4;
  const int cw = (t & 15) * 4;

  auto load_tile = [&](int step) {
    const int k0 = step * BK;
    const bool base = (k0 < IN_F);
#pragma unroll
    for (int j = 0; j < 8; ++j) {
      const int row = j * 16 + rw;
      const float* p = base
        ? (bw + (size_t)(bn0 + row) * IN_F + k0 + cw)
        : (sw + (size_t)(bn0 + row) * (size_t)(IN_F * GSZ) + (k0 - IN_F) + cw);
      rB[j] = *(const float4*)p;
    }
    if (base) {
#pragma unroll
      for (int j = 0; j < 8; ++j) {
        const int row = j * 16 + rw;
        rA[j] = *(const float4*)(x + (size_t)(bm0 + row) * IN_F + k0 + cw);
      }
    } else {
      const int i0  = (k0 - IN_F) >> 3;
      const int row = t >> 1;
      rA[0] = *(const float4*)(x + (size_t)(bm0 + row) * IN_F + i0 + (t & 1) * 4);
    }
  };

  auto store_tile = [&](int step) {
    const int k0 = step * BK;
    const bool base = (k0 < IN_F);
#pragma unroll
    for (int j = 0; j < 8; ++j) {
      const int row = j * 16 + rw;
      uint2 v;
      v.x = pk2(rB[j].x, rB[j].y);
      v.y = pk2(rB[j].z, rB[j].w);
      *(uint2*)&tB[row][cw] = v;
    }
    if (base) {
#pragma unroll
      for (int j = 0; j < 8; ++j) {
        const int row = j * 16 + rw;
        uint2 v;
        v.x = pk2(silu_f(rA[j].x), silu_f(rA[j].y));
        v.y = pk2(silu_f(rA[j].z), silu_f(rA[j].w));
        *(uint2*)&tA[row][cw] = v;
      }
    } else {
      const int row  = t >> 1;
      const int half = t & 1;
      const float* xv = (const float*)&rA[0];
#pragma unroll
      for (int c = 0; c < 4; ++c) {
        const float tb = xv[c] * CS;
        union { unsigned u[4]; int4 v4; } pkv;
#pragma unroll
        for (int g = 0; g < 8; g += 2) {
          const float t0 = tb - gsc[g];
          const float t1 = tb - gsc[g + 1];
          const float e0 = __builtin_amdgcn_exp2f(-(t0 * t0));
          const float e1 = __builtin_amdgcn_exp2f(-(t1 * t1));
          pkv.u[g >> 1] = pk2(e0, e1);
        }
        const int kc = (half * 4 + c) * 8;
        *(int4*)&tA[row][kc] = pkv.v4;
      }
    }
  };

  auto compute_tile = [&]() {
    const int r  = lane & 15;
    const int kq = (lane >> 4) * 8;
#pragma unroll
    for (int kh = 0; kh < 2; ++kh) {
      short8 af[4], bf[4];
#pragma unroll
      for (int m = 0; m < 4; ++m)
        af[m] = *(const short8*)&tA[wr + m * 16 + r][kh * 32 + kq];
#pragma unroll
      for (int n = 0; n < 4; ++n)
        bf[n] = *(const short8*)&tB[wc + n * 16 + r][kh * 32 + kq];
#pragma unroll
      for (int m = 0; m < 4; ++m)
#pragma unroll
        for (int n = 0; n < 4; ++n)
          acc[m][n] = __builtin_amdgcn_mfma_f32_16x16x32_bf16(af[m], bf[n], acc[m][n], 0, 0, 0);
    }
  };

  load_tile(0);
  for (int step = 0; step < NT; ++step) {
    store_tile(step);
    __syncthreads();
    if (step + 1 < NT) load_tile(step + 1);
    compute_tile();
    __syncthreads();
  }

  const int col = lane & 15;
  const int rr  = (lane >> 4) * 4;
#pragma unroll
  for (int m = 0; m < 4; ++m) {
    const int gr = bm0 + wr + m * 16 + rr;
#pragma unroll
    for (int n = 0; n < 4; ++n) {
      const int gc = bn0 + wc + n * 16 + col;
      const float bias = bb[gc];
#pragma unroll
      for (int j = 0; j < 4; ++j)
        out[(size_t)(gr + j) * OUT_F + gc] = acc[m][n][j] + bias;
    }
  }
}

} // namespace

extern "C" void kernel_launch(void* const* d_in, const int* in_sizes, int n_in,
                              void* d_out, int out_size, void* d_ws, size_t ws_size,
                              hipStream_t stream) {
  const float *x, *bw, *bb, *sw;
  if (in_sizes[0] == OUT_F) {            // alphabetical order guard
    bb = (const float*)d_in[0];
    bw = (const float*)d_in[1];
    sw = (const float*)d_in[2];
    x  = (const float*)d_in[3];
  } else {
    x  = (const float*)d_in[0];
    bw = (const float*)d_in[1];
    bb = (const float*)d_in[2];
    sw = (const float*)d_in[3];
  }
  float* out = (float*)d_out;
  const int rows = (in_sizes[0] == OUT_F) ? in_sizes[3] / IN_F : in_sizes[0] / IN_F;

  if (ws_size >= WS_NEEDED && d_ws != nullptr && (rows % BM) == 0) {
    hipLaunchKernelGGL(wprep, dim3(2048), dim3(256), 0, stream, bw, sw, (char*)d_ws);
    dim3 grid(NBLK, rows / BM);          // 4 x 128 = 512 blocks -> 2 blocks/CU
    hipLaunchKernelGGL(kan_fast, grid, dim3(512), 0, stream,
                       x, bb, (const char*)d_ws, out);
  } else {
    dim3 grid(rows / 128, OUT_F / 128);
    hipLaunchKernelGGL(kan_slow, grid, dim3(256), 0, stream, x, bw, bb, sw, out);
  }
}

// Round 9
// 191.224 us; speedup vs baseline: 1.0814x; 1.0381x over previous
//
#include <hip/hip_runtime.h>
#include <stdint.h>

namespace {

constexpr int IN_F = 1024;
constexpr int OUT_F = 1024;
constexpr int GSZ = 8;
constexpr int KTOT = IN_F + IN_F * GSZ;   // 9216
constexpr int BK = 64;
constexpr int NT = KTOT / BK;             // 144 (even)
constexpr int NBASE = IN_F / BK;          // 16 base-path steps

// fast-path geometry: 64x256 tile, 4 waves (wave tile 64x64), B direct from L2
constexpr int BM = 64, BN = 256;
constexpr int NBLK = OUT_F / BN;          // 4
constexpr size_t IMG_BYTES = (size_t)BN * BK * 2;              // 32 KB per (nb,step)
constexpr size_t WS_NEEDED = (size_t)NBLK * NT * IMG_BYTES;    // 18.87 MB

constexpr double H_D     = 4.0 / 7.0;
constexpr double INVD_D  = 1.0 / (H_D + 1e-6);
constexpr double L2E_D   = 1.4426950408889634;
constexpr double SQL2E_D = 1.2011224087864498;       // sqrt(log2 e)
constexpr double CS_D    = INVD_D * SQL2E_D;         // exp(-(d*invd)^2)=exp2(-((d*CS)^2))
constexpr double DLT_D   = H_D * CS_D;               // grid spacing, scaled

using short8 = __attribute__((ext_vector_type(8))) short;
using f32x4  = __attribute__((ext_vector_type(4))) float;

__device__ __forceinline__ unsigned cvt_pk(float lo, float hi) {
  unsigned r;
  asm("v_cvt_pk_bf16_f32 %0, %1, %2" : "=v"(r) : "v"(lo), "v"(hi));
  return r;
}
__device__ __forceinline__ float silu_f(float v) {
  float e = __builtin_amdgcn_exp2f(-v * (float)L2E_D);
  return v * __builtin_amdgcn_rcpf(1.0f + e);
}
// XOR-swizzled byte offset in a [rows][64 bf16] tile, row stride 128B.
__device__ __forceinline__ int swz(int row, int kk) {
  return (row * 128 + kk * 2) ^ ((row & 7) << 4);
}

// ---------------- weight prep: f32 -> bf16, swizzled fragment images ----------------
__global__ void wprep(const float* __restrict__ bw, const float* __restrict__ sw,
                      char* __restrict__ wimg)
{
  const int total = NBLK * NT * BN * 8;   // 16B chunks (8 bf16 each)
  for (int idx = blockIdx.x * blockDim.x + threadIdx.x; idx < total;
       idx += gridDim.x * blockDim.x) {
    const int kk8  = idx & 7;
    const int row  = (idx >> 3) & (BN - 1);
    const int rest = idx >> 11;           // nb*NT + step
    const int step = rest % NT;
    const int nb   = rest / NT;
    const int o    = nb * BN + row;
    const int k    = step * BK + kk8 * 8;
    const float* src = (k < IN_F)
      ? (bw + (size_t)o * IN_F + k)
      : (sw + (size_t)o * (size_t)(IN_F * GSZ) + (k - IN_F));
    const float4 a = ((const float4*)src)[0];
    const float4 b = ((const float4*)src)[1];
    int4 v;
    v.x = (int)cvt_pk(a.x, a.y);
    v.y = (int)cvt_pk(a.z, a.w);
    v.z = (int)cvt_pk(b.x, b.y);
    v.w = (int)cvt_pk(b.z, b.w);
    *(int4*)(wimg + (size_t)rest * IMG_BYTES + swz(row, kk8 * 8)) = v;
  }
}

// ------- fast main kernel: B frags direct global->reg, A via 16 KB LDS db -------
__global__ __launch_bounds__(256, 2)
void kan_fast(const float* __restrict__ x, const float* __restrict__ bb,
              const char* __restrict__ wimg, float* __restrict__ out)
{
  __shared__ char tA[2][BM * BK * 2];     // 2 x 8 KB, swizzled

  const int t    = threadIdx.x;
  const int lane = t & 63;
  const int wid  = t >> 6;                // 0..3
  const int wc   = wid * 64;              // wave col offset (wave tile 64x64)

  // XCD-pinned bijective decode: blocks with weight-panel nb land on XCDs {2nb,2nb+1}
  const int d   = blockIdx.x;
  const int r8  = d & 7;
  const int nb  = r8 >> 1;
  const int my  = ((d >> 3) << 1) | (r8 & 1);
  const int bm0 = my * BM;
  const int bn0 = nb * BN;
  const char* img = wimg + (size_t)nb * NT * IMG_BYTES;

  const float CSf  = (float)CS_D;
  const float C0f  = (float)(-2.0 * CS_D);
  const float TDLT = (float)(2.0 * DLT_D);
  float Kc[7];
#pragma unroll
  for (int g = 0; g < 7; ++g) {
    const double cg  = (-2.0 + g * H_D) * CS_D;
    const double cg1 = (-2.0 + (g + 1) * H_D) * CS_D;
    Kc[g] = __builtin_amdgcn_exp2f((float)(-DLT_D * (cg + cg1)));
  }

  f32x4 acc[4][4];
#pragma unroll
  for (int m = 0; m < 4; ++m)
#pragma unroll
    for (int n = 0; n < 4; ++n) acc[m][n] = (f32x4)0.0f;

  // fragment lane geometry (shared by A ds_reads and B global reads)
  const int fr = lane & 15;
  const int kq = (lane >> 4) * 8;

  // step-invariant per-lane byte offsets of this wave's 8 B fragments in the image
  int boff[8];
#pragma unroll
  for (int n = 0; n < 4; ++n)
#pragma unroll
    for (int kh = 0; kh < 2; ++kh)
      boff[n * 2 + kh] = swz(wc + n * 16 + fr, kh * 32 + kq);

  short8 bE[8], bO[8];                    // B frag ping-pong (32+32 VGPR)
  float4 xE[4], xO[4];                    // x prefetch ping-pong

  auto issue_B = [&](int step, short8 (&br)[8]) {
    const char* base = img + (size_t)step * IMG_BYTES;
#pragma unroll
    for (int j = 0; j < 8; ++j)
      br[j] = *(const short8*)(base + boff[j]);
  };

  const int prow = t >> 2;                // 0..63 (A-tile row)
  const int pcol = t & 3;

  auto load_x = [&](int step, float4 (&xr)[4]) {
    const int k0 = step * BK;
    if (k0 < IN_F) {                      // base: 16 f32/thread
      const float* p = x + (size_t)(bm0 + prow) * IN_F + k0 + pcol * 16;
#pragma unroll
      for (int j = 0; j < 4; ++j) xr[j] = ((const float4*)p)[j];
    } else {                              // spline: 2 f32/thread
      const int i0 = (k0 - IN_F) >> 3;
      const float2 v = *(const float2*)(x + (size_t)(bm0 + prow) * IN_F + i0 + pcol * 2);
      xr[0].x = v.x; xr[0].y = v.y;
    }
  };

  auto conv_A = [&](int step, const float4 (&xr)[4], char* dstA) {
    if (step < NBASE) {
      unsigned q[8];
#pragma unroll
      for (int j = 0; j < 4; ++j) {
        q[2 * j]     = cvt_pk(silu_f(xr[j].x), silu_f(xr[j].y));
        q[2 * j + 1] = cvt_pk(silu_f(xr[j].z), silu_f(xr[j].w));
      }
      const int kc0 = pcol * 16;
      *(int4*)(dstA + swz(prow, kc0))     = make_int4(q[0], q[1], q[2], q[3]);
      *(int4*)(dstA + swz(prow, kc0 + 8)) = make_int4(q[4], q[5], q[6], q[7]);
    } else {
#pragma unroll
      for (int c = 0; c < 2; ++c) {
        const float xv = c ? xr[0].y : xr[0].x;
        const float tb = xv * CSf;
        const float d0 = tb - C0f;
        float e = __builtin_amdgcn_exp2f(-(d0 * d0));   // e_0
        const float r = __builtin_amdgcn_exp2f(tb * TDLT);
        unsigned q[4];
#pragma unroll
        for (int g = 0; g < 4; ++g) {
          const float a = e;                  // e_{2g}
          const float b = a * r * Kc[2 * g];  // e_{2g+1}
          q[g] = cvt_pk(a, b);
          if (g < 3) e = b * r * Kc[2 * g + 1];
        }
        *(int4*)(dstA + swz(prow, (pcol * 2 + c) * 8)) = make_int4(q[0], q[1], q[2], q[3]);
      }
    }
  };

  // one K-step: A frags from LDS, B frags already in regs; one sync per step
  auto step_body = [&](int s, char* curA, char* nxtA,
                       short8 (&bCur)[8], short8 (&bNxt)[8],
                       const float4 (&xconv)[4], float4 (&xload)[4]) {
    if (s + 1 < NT) issue_B(s + 1, bNxt);        // global->reg, lands during MFMA
    if (s + 2 < NT) load_x(s + 2, xload);
    if (s + 1 < NT) conv_A(s + 1, xconv, nxtA);  // VALU + ds_write -> nxtA
    // kh=0 half
    short8 af[4];
#pragma unroll
    for (int m = 0; m < 4; ++m)
      af[m] = *(const short8*)(curA + swz(m * 16 + fr, kq));
#pragma unroll
    for (int m = 0; m < 4; ++m)
#pragma unroll
      for (int n = 0; n < 4; ++n)
        acc[m][n] = __builtin_amdgcn_mfma_f32_16x16x32_bf16(af[m], bCur[n * 2], acc[m][n], 0, 0, 0);
    // kh=1 half
#pragma unroll
    for (int m = 0; m < 4; ++m)
      af[m] = *(const short8*)(curA + swz(m * 16 + fr, 32 + kq));
#pragma unroll
    for (int m = 0; m < 4; ++m)
#pragma unroll
      for (int n = 0; n < 4; ++n)
        acc[m][n] = __builtin_amdgcn_mfma_f32_16x16x32_bf16(af[m], bCur[n * 2 + 1], acc[m][n], 0, 0, 0);
    __syncthreads();                             // publish nxtA; WAR-protect curA
  };

  // prologue
  load_x(0, xE);
  load_x(1, xO);
  issue_B(0, bE);
  conv_A(0, xE, tA[0]);
  __syncthreads();                   // A(0) visible (B(0) waited by first use)

  for (int s = 0; s < NT; s += 2) {
    step_body(s,     tA[0], tA[1], bE, bO, xO, xE);
    step_body(s + 1, tA[1], tA[0], bO, bE, xE, xO);
  }

  // epilogue: C/D mapping col=lane&15, row=(lane>>4)*4+reg (verified r2-r8)
  const int col = lane & 15;
  const int rr  = (lane >> 4) * 4;
#pragma unroll
  for (int m = 0; m < 4; ++m) {
    const int gr = bm0 + m * 16 + rr;
#pragma unroll
    for (int n = 0; n < 4; ++n) {
      const int gc = bn0 + wc + n * 16 + col;
      const float bias = bb[gc];
#pragma unroll
      for (int j = 0; j < 4; ++j)
        out[(size_t)(gr + j) * OUT_F + gc] = acc[m][n][j] + bias;
    }
  }
}

// ---------------- fallback: round-2 verified kernel (unchanged) ----------------
constexpr int SLDK = 64 + 8;

__device__ __forceinline__ unsigned f2bf(float f) {
  unsigned u = __float_as_uint(f);
  return (u + 0x7fffu + ((u >> 16) & 1u)) >> 16;
}
__device__ __forceinline__ unsigned pk2(float lo, float hi) {
  return f2bf(lo) | (f2bf(hi) << 16);
}

__global__ __launch_bounds__(256)
void kan_slow(const float* __restrict__ x, const float* __restrict__ bw,
              const float* __restrict__ bb, const float* __restrict__ sw,
              float* __restrict__ out)
{
  __shared__ unsigned short tA[128][SLDK];
  __shared__ unsigned short tB[128][SLDK];

  const int t    = threadIdx.x;
  const int lane = t & 63;
  const int wid  = t >> 6;
  const int wr   = (wid >> 1) * 64;
  const int wc   = (wid & 1) * 64;
  const int bm0  = blockIdx.x * 128;
  const int bn0  = blockIdx.y * 128;

  const float CS = (float)CS_D;
  float gsc[GSZ];
#pragma unroll
  for (int g = 0; g < GSZ; ++g)
    gsc[g] = (float)((-2.0 + g * H_D) * CS_D);

  f32x4 acc[4][4];
#pragma unroll
  for (int m = 0; m < 4; ++m)
#pragma unroll
    for (int n = 0; n < 4; ++n) acc[m][n] = (f32x4)0.0f;

  float4 rA[8], rB[8];
  const int rw = t >> 4;
  const int cw = (t & 15) * 4;

  auto load_tile = [&](int step) {
    const int k0 = step * BK;
    const bool base = (k0 < IN_F);
#pragma unroll
    for (int j = 0; j < 8; ++j) {
      const int row = j * 16 + rw;
      const float* p = base
        ? (bw + (size_t)(bn0 + row) * IN_F + k0 + cw)
        : (sw + (size_t)(bn0 + row) * (size_t)(IN_F * GSZ) + (k0 - IN_F) + cw);
      rB[j] = *(const float4*)p;
    }
    if (base) {
#pragma unroll
      for (int j = 0; j < 8; ++j) {
        const int row = j * 16 + rw;
        rA[j] = *(const float4*)(x + (size_t)(bm0 + row) * IN_F + k0 + cw);
      }
    } else {
      const int i0  = (k0 - IN_F) >> 3;
      const int row = t >> 1;
      rA[0] = *(const float4*)(x + (size_t)(bm0 + row) * IN_F + i0 + (t & 1) * 4);
    }
  };

  auto store_tile = [&](int step) {
    const int k0 = step * BK;
    const bool base = (k0 < IN_F);
#pragma unroll
    for (int j = 0; j < 8; ++j) {
      const int row = j * 16 + rw;
      uint2 v;
      v.x = pk2(rB[j].x, rB[j].y);
      v.y = pk2(rB[j].z, rB[j].w);
      *(uint2*)&tB[row][cw] = v;
    }
    if (base) {
#pragma unroll
      for (int j = 0; j < 8; ++j) {
        const int row = j * 16 + rw;
        uint2 v;
        v.x = pk2(silu_f(rA[j].x), silu_f(rA[j].y));
        v.y = pk2(silu_f(rA[j].z), silu_f(rA[j].w));
        *(uint2*)&tA[row][cw] = v;
      }
    } else {
      const int row  = t >> 1;
      const int half = t & 1;
      const float* xv = (const float*)&rA[0];
#pragma unroll
      for (int c = 0; c < 4; ++c) {
        const float tb = xv[c] * CS;
        union { unsigned u[4]; int4 v4; } pkv;
#pragma unroll
        for (int g = 0; g < 8; g += 2) {
          const float t0 = tb - gsc[g];
          const float t1 = tb - gsc[g + 1];
          const float e0 = __builtin_amdgcn_exp2f(-(t0 * t0));
          const float e1 = __builtin_amdgcn_exp2f(-(t1 * t1));
          pkv.u[g >> 1] = pk2(e0, e1);
        }
        const int kc = (half * 4 + c) * 8;
        *(int4*)&tA[row][kc] = pkv.v4;
      }
    }
  };

  auto compute_tile = [&]() {
    const int r  = lane & 15;
    const int kq = (lane >> 4) * 8;
#pragma unroll
    for (int kh = 0; kh < 2; ++kh) {
      short8 af[4], bf[4];
#pragma unroll
      for (int m = 0; m < 4; ++m)
        af[m] = *(const short8*)&tA[wr + m * 16 + r][kh * 32 + kq];
#pragma unroll
      for (int n = 0; n < 4; ++n)
        bf[n] = *(const short8*)&tB[wc + n * 16 + r][kh * 32 + kq];
#pragma unroll
      for (int m = 0; m < 4; ++m)
#pragma unroll
        for (int n = 0; n < 4; ++n)
          acc[m][n] = __builtin_amdgcn_mfma_f32_16x16x32_bf16(af[m], bf[n], acc[m][n], 0, 0, 0);
    }
  };

  load_tile(0);
  for (int step = 0; step < NT; ++step) {
    store_tile(step);
    __syncthreads();
    if (step + 1 < NT) load_tile(step + 1);
    compute_tile();
    __syncthreads();
  }

  const int col = lane & 15;
  const int rr  = (lane >> 4) * 4;
#pragma unroll
  for (int m = 0; m < 4; ++m) {
    const int gr = bm0 + wr + m * 16 + rr;
#pragma unroll
    for (int n = 0; n < 4; ++n) {
      const int gc = bn0 + wc + n * 16 + col;
      const float bias = bb[gc];
#pragma unroll
      for (int j = 0; j < 4; ++j)
        out[(size_t)(gr + j) * OUT_F + gc] = acc[m][n][j] + bias;
    }
  }
}

} // namespace

extern "C" void kernel_launch(void* const* d_in, const int* in_sizes, int n_in,
                              void* d_out, int out_size, void* d_ws, size_t ws_size,
                              hipStream_t stream) {
  const float *x, *bw, *bb, *sw;
  if (in_sizes[0] == OUT_F) {            // alphabetical order guard
    bb = (const float*)d_in[0];
    bw = (const float*)d_in[1];
    sw = (const float*)d_in[2];
    x  = (const float*)d_in[3];
  } else {
    x  = (const float*)d_in[0];
    bw = (const float*)d_in[1];
    bb = (const float*)d_in[2];
    sw = (const float*)d_in[3];
  }
  float* out = (float*)d_out;
  const int rows = (in_sizes[0] == OUT_F) ? in_sizes[3] / IN_F : in_sizes[0] / IN_F;

  if (ws_size >= WS_NEEDED && d_ws != nullptr && (rows % (2 * BM)) == 0) {
    hipLaunchKernelGGL(wprep, dim3(2048), dim3(256), 0, stream, bw, sw, (char*)d_ws);
    const int nblocks = NBLK * (rows / BM);   // 512
    hipLaunchKernelGGL(kan_fast, dim3(nblocks), dim3(256), 0, stream,
                       x, bb, (const char*)d_ws, out);
  } else {
    dim3 grid(rows / 128, OUT_F / 128);
    hipLaunchKernelGGL(kan_slow, grid, dim3(256), 0, stream, x, bw, bb, sw, out);
  }
}